// Round 8
// baseline (47.876 us; speedup 1.0000x reference)
//
#include <hip/hip_runtime.h>

#define SEQ 197
#define NP 196
#define NHEADS 12
#define CUT 98                    // int(0.5 * 196)
#define VECS_PER_BATCH 37632      // 3*224*224/4 float4 per batch
#define BPB 8                     // blocks per batch
#define VECS_PER_BLOCK 4704       // 37632 / 8
#define ROWS_PER_BLOCK 84         // channel-rows per block slice (672/8)

typedef float f4 __attribute__((ext_vector_type(4)));

// Fused: each block (b = bid&255, j = bid>>8) computes the top-98 patch mask
// (only for the <=6 patch rows its slice touches), then streams its 1/8 of
// the image. b = bid&255 puts a batch's 8 blocks on the SAME XCD so the
// attention rows hit L2 after the first block.
//
// Stores MUST be nontemporal: regular stores leave output dirty in the
// non-coherent per-XCD L2s; post-timing readback then sees stale HBM
// (round-4 failure). Lane-CONSECUTIVE addressing per store instruction is
// mandatory: NT stores bypass L2, half-covered lines can't write-combine
// (round-5 failure: 32B/lane pairs -> 82.5 us).
//
// The first TWO streaming iterations are prefetched UNCONDITIONALLY before
// the x-load + rank scan: at launch every block scans simultaneously (pure
// VALU, memory idle ~3 us); these in-flight loads keep HBM busy under the
// scan at the cost of ~8 MB unpredicated fetch.
__global__ __launch_bounds__(256) void fused_fixation_kernel(
        const float* __restrict__ x,
        const float* __restrict__ img,
        float* __restrict__ out) {
    const int bid = blockIdx.x;
    const int b = bid & 255;      // batch index
    const int j = bid >> 8;       // sub-block within batch
    const int t = threadIdx.x;

    __shared__ __align__(16) unsigned long long sK[NP];
    __shared__ float sM[NP];

    const f4* imgb = (const f4*)img + (size_t)b * VECS_PER_BATCH;
    f4*       outb = (f4*)out       + (size_t)b * VECS_PER_BATCH;
    const int vstart = j * VECS_PER_BLOCK + t;
    const int vend   = (j + 1) * VECS_PER_BLOCK;

    // 0) unconditional prefetch of iterations 0 and 1 (in flight during scan)
    f4 pf0 = imgb[vstart];
    f4 pf1 = imgb[vstart + 256];

    // 1) head-summed CLS->patch attention -> sortable u64 key
    if (t < NP) {
        const float* base = x + (size_t)b * NHEADS * SEQ * SEQ + 1 + t;
        float a = 0.0f;
        #pragma unroll
        for (int h = 0; h < NHEADS; ++h)
            a += base[(size_t)h * SEQ * SEQ];
        unsigned int bits = __float_as_uint(a);
        // monotone map: larger float -> larger uint (finite values)
        unsigned int u = (bits & 0x80000000u) ? ~bits : (bits | 0x80000000u);
        sK[t] = ((unsigned long long)u << 32) | (unsigned int)(NP - 1 - t);
    }
    __syncthreads();

    // 2) rank ONLY the patch rows this block's slice touches (84 patches ->
    //    2 active waves; keys unique so one u64 compare reproduces top_k's
    //    stable descending order exactly)
    {
        const int y0   = (j * ROWS_PER_BLOCK) % 224;
        const int yend = y0 + ROWS_PER_BLOCK - 1;         // may wrap past 223
        const int r0   = y0 >> 4;
        const int r1   = (yend <= 223 ? yend : 223) >> 4;
        const int seg0 = r1 - r0 + 1;
        const int wrapRows = (yend > 223) ? (((yend - 224) >> 4) + 1) : 0;
        const int nneed = (seg0 + wrapRows) * 14;

        if (t < nneed) {
            const int local = t / 14;
            const int pc    = t - local * 14;
            const int pr    = (local < seg0) ? (r0 + local) : (local - seg0);
            const int pidx  = pr * 14 + pc;
            const unsigned long long mykey = sK[pidx];
            int rank = 0;
            #pragma unroll 4
            for (int p = 0; p < NP; ++p)
                rank += (sK[p] > mykey) ? 1 : 0;   // uniform LDS broadcast
            sM[pidx] = (rank < CUT) ? 1.0f : 0.0f;
        }
    }
    __syncthreads();

    // 3a) drain the prefetched iterations: multiply by mask (m in {0,1},
    //     multiply is exact and matches the reference's img * mask)
    {
        int v = vstart;
        int x4 = v % 56;
        int yy = (v / 56) % 224;
        pf0 *= sM[(yy >> 4) * 14 + (x4 >> 2)];
        __builtin_nontemporal_store(pf0, &outb[v]);

        v = vstart + 256;
        x4 = v % 56;
        yy = (v / 56) % 224;
        pf1 *= sM[(yy >> 4) * 14 + (x4 >> 2)];
        __builtin_nontemporal_store(pf1, &outb[v]);
    }

    // 3b) stream the rest: predicated float4 in, NT float4 out
    #pragma unroll 2
    for (int v = vstart + 512; v < vend; v += 256) {
        int x4 = v % 56;                    // float4 col in a 224-px row
        int yy = (v / 56) % 224;            // pixel row (channel-independent)
        float m = sM[(yy >> 4) * 14 + (x4 >> 2)];
        f4 p = {0.0f, 0.0f, 0.0f, 0.0f};
        if (m != 0.0f)                      // exec-masked: zero patches never fetched
            p = imgb[v];
        __builtin_nontemporal_store(p, &outb[v]);
    }
}

extern "C" void kernel_launch(void* const* d_in, const int* in_sizes, int n_in,
                              void* d_out, int out_size, void* d_ws, size_t ws_size,
                              hipStream_t stream) {
    const float* x   = (const float*)d_in[0];   // [B, 12, 197, 197] fp32
    const float* img = (const float*)d_in[1];   // [B, 3, 224, 224] fp32
    float* out = (float*)d_out;                 // [B, 3*224*224] fp32

    const int B = in_sizes[0] / (NHEADS * SEQ * SEQ);   // 256

    fused_fixation_kernel<<<B * BPB, 256, 0, stream>>>(x, img, out);
}

// Round 9
// 47.094 us; speedup vs baseline: 1.0166x; 1.0166x over previous
//
#include <hip/hip_runtime.h>

#define SEQ 197
#define NP 196
#define NHEADS 12
#define CUT 98                    // int(0.5 * 196)
#define VECS_PER_BATCH 37632      // 3*224*224/4 float4 per batch
#define BPB 8                     // blocks per batch
#define VECS_PER_BLOCK 4704       // 37632 / 8
#define ROWS_PER_BLOCK 84         // channel-rows per block slice (672/8)

typedef float f4 __attribute__((ext_vector_type(4)));

// Fused: each block (b = bid&255, j = bid>>8) computes the top-98 patch mask
// (only for the <=6 patch rows its slice touches), then streams its 1/8 of
// the image. b = bid&255 puts a batch's 8 blocks on the SAME XCD so the
// attention rows hit L2 after the first block.
//
// Hard-won constraints (do not "optimize" these away):
// - Stores MUST be nontemporal: regular stores leave output dirty in the
//   non-coherent per-XCD L2s; post-timing readback sees stale HBM
//   (round-4 failure, absmax 4.94).
// - Lane-CONSECUTIVE addressing per store instruction: NT stores bypass L2,
//   half-covered lines can't write-combine (round-5: 32B/lane -> 82.5 us).
// - NO unconditional prefetch of image data before the scan: the +8 MB of
//   unpredicated fetch costs more than the prologue idle it hides
//   (round-8: 47.1 -> 47.9 us).
//
// Rank scan uses u64 sortable keys: (monotone-mapped float bits << 32) |
// (195 - t). Unique keys; equal floats rank by ascending index — exactly
// lax.top_k's stable descending order. One u64 compare per element.
__global__ __launch_bounds__(256) void fused_fixation_kernel(
        const float* __restrict__ x,
        const float* __restrict__ img,
        float* __restrict__ out) {
    const int bid = blockIdx.x;
    const int b = bid & 255;      // batch index
    const int j = bid >> 8;       // sub-block within batch
    const int t = threadIdx.x;

    __shared__ __align__(16) unsigned long long sK[NP];
    __shared__ float sM[NP];

    // 1) head-summed CLS->patch attention -> sortable u64 key
    if (t < NP) {
        const float* base = x + (size_t)b * NHEADS * SEQ * SEQ + 1 + t;
        float a = 0.0f;
        #pragma unroll
        for (int h = 0; h < NHEADS; ++h)
            a += base[(size_t)h * SEQ * SEQ];
        unsigned int bits = __float_as_uint(a);
        // monotone map: larger float -> larger uint (finite values)
        unsigned int u = (bits & 0x80000000u) ? ~bits : (bits | 0x80000000u);
        sK[t] = ((unsigned long long)u << 32) | (unsigned int)(NP - 1 - t);
    }
    __syncthreads();

    // 2) rank ONLY the patch rows this block's slice touches (84 patches ->
    //    2 active waves instead of 4; halves per-SIMD scan issue pressure)
    {
        const int y0   = (j * ROWS_PER_BLOCK) % 224;
        const int yend = y0 + ROWS_PER_BLOCK - 1;         // may wrap past 223
        const int r0   = y0 >> 4;
        const int r1   = (yend <= 223 ? yend : 223) >> 4;
        const int seg0 = r1 - r0 + 1;
        const int wrapRows = (yend > 223) ? (((yend - 224) >> 4) + 1) : 0;
        const int nneed = (seg0 + wrapRows) * 14;

        if (t < nneed) {
            const int local = t / 14;
            const int pc    = t - local * 14;
            const int pr    = (local < seg0) ? (r0 + local) : (local - seg0);
            const int pidx  = pr * 14 + pc;
            const unsigned long long mykey = sK[pidx];
            int rank = 0;
            #pragma unroll 4
            for (int p = 0; p < NP; ++p)
                rank += (sK[p] > mykey) ? 1 : 0;   // uniform LDS broadcast
            sM[pidx] = (rank < CUT) ? 1.0f : 0.0f;
        }
    }
    __syncthreads();

    // 3) stream this block's image slice: predicated float4 in, NT float4 out
    const f4* imgb = (const f4*)img + (size_t)b * VECS_PER_BATCH;
    f4*       outb = (f4*)out       + (size_t)b * VECS_PER_BATCH;

    const int vend = (j + 1) * VECS_PER_BLOCK;
    #pragma unroll 2
    for (int v = j * VECS_PER_BLOCK + t; v < vend; v += 256) {
        int x4 = v % 56;                    // float4 col in a 224-px row
        int yy = (v / 56) % 224;            // pixel row (channel-independent)
        float m = sM[(yy >> 4) * 14 + (x4 >> 2)];
        f4 p = {0.0f, 0.0f, 0.0f, 0.0f};
        if (m != 0.0f)                      // exec-masked: zero patches never fetched
            p = imgb[v];
        __builtin_nontemporal_store(p, &outb[v]);
    }
}

extern "C" void kernel_launch(void* const* d_in, const int* in_sizes, int n_in,
                              void* d_out, int out_size, void* d_ws, size_t ws_size,
                              hipStream_t stream) {
    const float* x   = (const float*)d_in[0];   // [B, 12, 197, 197] fp32
    const float* img = (const float*)d_in[1];   // [B, 3, 224, 224] fp32
    float* out = (float*)d_out;                 // [B, 3*224*224] fp32

    const int B = in_sizes[0] / (NHEADS * SEQ * SEQ);   // 256

    fused_fixation_kernel<<<B * BPB, 256, 0, stream>>>(x, img, out);
}